// Round 1
// baseline (284.287 us; speedup 1.0000x reference)
//
#include <hip/hip_runtime.h>

// GraphiT-GT layer, fused. B=32, N=128, D=64, H=8, DH=8.
// Kernel 1: QKV projections (fp32 matvec, K pre-scaled by DH^-0.5).
// Kernel 2: per (b,i) block: e-row tile -> bf16 LDS -> MFMA E=e@We ->
//           scores (DPP head-reduce) -> exp*k_RW -> attn -> O-proj ->
//           LN1 -> FFN -> LN2 -> out. S matrix / attn never hit HBM.

#define NB 32
#define NN 128
#define ND 64

typedef __attribute__((ext_vector_type(8))) __bf16 bf16x8;
typedef __attribute__((ext_vector_type(8))) unsigned short u16x8;
typedef __attribute__((ext_vector_type(4))) float f32x4;

static __device__ __forceinline__ unsigned short f2bf(float x) {
  unsigned u = __float_as_uint(x);
  u += 0x7fffu + ((u >> 16) & 1u);   // RNE (inputs are finite, no NaN handling needed)
  return (unsigned short)(u >> 16);
}

// v + dpp_perm(v): VALU-pipe cross-lane add (no LDS pipe traffic)
#define DPP_ADD(v, ctrl) \
  ((v) + __int_as_float(__builtin_amdgcn_update_dpp(0, __float_as_int(v), (ctrl), 0xf, 0xf, true)))

static __device__ __forceinline__ float wsum64(float v) {
  v += __shfl_xor(v, 1, 64);
  v += __shfl_xor(v, 2, 64);
  v += __shfl_xor(v, 4, 64);
  v += __shfl_xor(v, 8, 64);
  v += __shfl_xor(v, 16, 64);
  v += __shfl_xor(v, 32, 64);
  return v;
}

__global__ __launch_bounds__(64) void qkv_kernel(
    const float* __restrict__ h, const float* __restrict__ Wq,
    const float* __restrict__ Wk, const float* __restrict__ Wv,
    float* __restrict__ Q, float* __restrict__ K, float* __restrict__ V) {
  const int r = blockIdx.x;
  const int t = threadIdx.x;
  __shared__ float hrow[ND];
  hrow[t] = h[(size_t)r * ND + t];
  __syncthreads();
  float q = 0.f, k = 0.f, v = 0.f;
#pragma unroll 8
  for (int d = 0; d < ND; ++d) {
    const float hv = hrow[d];
    q = fmaf(hv, Wq[d * ND + t], q);
    k = fmaf(hv, Wk[d * ND + t], k);
    v = fmaf(hv, Wv[d * ND + t], v);
  }
  Q[(size_t)r * ND + t] = q;
  K[(size_t)r * ND + t] = k * 0.35355339059327373f;  // DH^-0.5 folded into K
  V[(size_t)r * ND + t] = v;
}

__global__ __launch_bounds__(256) void fused_kernel(
    const float* __restrict__ h, const float* __restrict__ e,
    const float* __restrict__ kRW, const float* __restrict__ We,
    const float* __restrict__ Wo, const float* __restrict__ bo,
    const float* __restrict__ g1, const float* __restrict__ be1,
    const float* __restrict__ W1, const float* __restrict__ b1,
    const float* __restrict__ W2, const float* __restrict__ b2,
    const float* __restrict__ g2, const float* __restrict__ be2,
    const float* __restrict__ Q, const float* __restrict__ K,
    const float* __restrict__ V, float* __restrict__ out) {
  const int blk = blockIdx.x;
  const int b = blk >> 7;
  const int i = blk & 127;
  const int tid = threadIdx.x;
  const int w = tid >> 6;       // wave 0..3
  const int L = tid & 63;       // lane
  const int quad = L >> 4;
  const int lrow = L & 15;

  // LDS: e rows padded 64->72 shorts (16B pad) so b128 fragment reads are 2-way max
  __shared__ __align__(16) unsigned short e_lds[NN * 72];   // 18 KB
  __shared__ __align__(16) unsigned short weT[ND * 72];     // 9 KB  (WeT[n][k] = We[k][n])
  __shared__ float S_lds[NN * 9];                           // S[j][h], pad 8->9
  __shared__ float krw_lds[NN];
  __shared__ float q_lds[ND];
  __shared__ float partN[4 * ND];
  __shared__ float partD[4 * ND];
  __shared__ float attn_lds[ND];
  __shared__ float n1_lds[ND];
  __shared__ float ff_lds[2 * ND];

  const size_t row = (size_t)b * NN + i;
  const float* e_bi = e + row * (NN * ND);
  const size_t kvbase = (size_t)b * NN * ND;

  // ---- stage e[b,i,:,:] (128x64 fp32) -> bf16 LDS, coalesced float4 loads ----
  {
    const int c = tid & 15;   // float4 column
    const int r0 = tid >> 4;  // 0..15
#pragma unroll
    for (int p = 0; p < 8; ++p) {
      const int rr = p * 16 + r0;
      const float4 vv = *(const float4*)(e_bi + rr * ND + c * 4);
      ushort4 sv = make_ushort4(f2bf(vv.x), f2bf(vv.y), f2bf(vv.z), f2bf(vv.w));
      *(ushort4*)(&e_lds[rr * 72 + c * 4]) = sv;
    }
  }
  // ---- stage We^T bf16 (coalesced read, scattered b16 write — one-time) ----
#pragma unroll
  for (int p = 0; p < 16; ++p) {
    const int idx = p * 256 + tid;
    const int kk = idx >> 6;
    const int nn = idx & 63;
    weT[nn * 72 + kk] = f2bf(We[idx]);
  }
  if (tid < NN) krw_lds[tid] = kRW[row * NN + tid];
  if (tid < ND) q_lds[tid] = Q[row * ND + tid];
  __syncthreads();

  // ---- MFMA: E[128x64] = e_bf[128x64] @ We_bf[64x64]; wave w owns j-rows [32w,32w+32) ----
  f32x4 acc[2][4];
#pragma unroll
  for (int mr = 0; mr < 2; ++mr)
#pragma unroll
    for (int n0 = 0; n0 < 4; ++n0) acc[mr][n0] = (f32x4){0.f, 0.f, 0.f, 0.f};

#pragma unroll
  for (int mr = 0; mr < 2; ++mr) {
    const int m0 = w * 2 + mr;
#pragma unroll
    for (int ks = 0; ks < 2; ++ks) {
      const bf16x8 av = __builtin_bit_cast(
          bf16x8, *(const u16x8*)(&e_lds[(m0 * 16 + lrow) * 72 + ks * 32 + quad * 8]));
#pragma unroll
      for (int n0 = 0; n0 < 4; ++n0) {
        const bf16x8 bv = __builtin_bit_cast(
            bf16x8, *(const u16x8*)(&weT[(n0 * 16 + lrow) * 72 + ks * 32 + quad * 8]));
        acc[mr][n0] = __builtin_amdgcn_mfma_f32_16x16x32_bf16(av, bv, acc[mr][n0], 0, 0, 0);
      }
    }
  }

  // ---- scores: s[h,j] = exp(clip(sum_{dout in h} E[j,dout]*Q[i,dout]*K[j,dout]))*kRW ----
  // C layout: col dout = n0*16+lrow, row j = m0*16+quad*4+reg.
  // Head reduction = 8-lane xor-group: quad_perm xor1, xor2, then row_half_mirror (DPP, VALU pipe).
#pragma unroll
  for (int mr = 0; mr < 2; ++mr) {
    const int m0 = w * 2 + mr;
#pragma unroll
    for (int n0 = 0; n0 < 4; ++n0) {
      const int dout = n0 * 16 + lrow;
      const int hh = dout >> 3;
      const float qv = q_lds[dout];
      float sv[4];
#pragma unroll
      for (int reg = 0; reg < 4; ++reg) {
        const int j = m0 * 16 + quad * 4 + reg;
        const float kv = K[kvbase + (size_t)j * ND + dout];
        float tv = acc[mr][n0][reg] * qv * kv;
        tv = DPP_ADD(tv, 0xB1);   // quad_perm [1,0,3,2]  (xor 1)
        tv = DPP_ADD(tv, 0x4E);   // quad_perm [2,3,0,1]  (xor 2)
        tv = DPP_ADD(tv, 0x141);  // row_half_mirror      (xor 4 within 8-group)
        sv[reg] = __expf(fminf(fmaxf(tv, -5.f), 5.f)) * krw_lds[j];
      }
      if ((L & 7) == 0) {
#pragma unroll
        for (int reg = 0; reg < 4; ++reg)
          S_lds[(m0 * 16 + quad * 4 + reg) * 9 + hh] = sv[reg];
      }
    }
  }
  __syncthreads();

  // ---- attn numerator/denominator: wave w sums its 32 j's ----
  {
    float nump = 0.f, denp = 0.f;
#pragma unroll 4
    for (int jj = 0; jj < 32; ++jj) {
      const int j = w * 32 + jj;
      const float s = S_lds[j * 9 + (L >> 3)];
      const float v = V[kvbase + (size_t)j * ND + L];
      nump = fmaf(s, v, nump);
      denp += s;
    }
    partN[w * ND + L] = nump;
    partD[w * ND + L] = denp;
  }
  __syncthreads();

  // ---- epilogue: single wave (64 lanes = 64 channels). Same-wave LDS needs no barrier;
  //      wave_barrier() pins compiler ordering. ----
  if (tid >= 64) return;
  const int t = tid;
  const float num = partN[t] + partN[64 + t] + partN[128 + t] + partN[192 + t];
  const float den = partD[t] + partD[64 + t] + partD[128 + t] + partD[192 + t];
  attn_lds[t] = num / fmaxf(den, 1e-6f);
  __builtin_amdgcn_wave_barrier();

  float o = bo[t];
#pragma unroll 8
  for (int d = 0; d < ND; ++d) o = fmaf(attn_lds[d], Wo[d * ND + t], o);
  const float h1 = h[row * ND + t] + o;

  const float m1 = wsum64(h1) * (1.f / 64.f);
  const float df1 = h1 - m1;
  const float v1 = wsum64(df1 * df1) * (1.f / 64.f);
  const float n1 = df1 * rsqrtf(v1 + 1e-5f) * g1[t] + be1[t];
  n1_lds[t] = n1;
  __builtin_amdgcn_wave_barrier();

  float a0 = b1[t], a1 = b1[64 + t];
#pragma unroll 8
  for (int d = 0; d < ND; ++d) {
    const float nv = n1_lds[d];
    a0 = fmaf(nv, W1[d * 128 + t], a0);
    a1 = fmaf(nv, W1[d * 128 + 64 + t], a1);
  }
  ff_lds[t] = fmaxf(a0, 0.f);
  ff_lds[64 + t] = fmaxf(a1, 0.f);
  __builtin_amdgcn_wave_barrier();

  float o2 = b2[t];
#pragma unroll 8
  for (int u = 0; u < 128; ++u) o2 = fmaf(ff_lds[u], W2[u * ND + t], o2);
  const float x = n1 + o2;

  const float m2 = wsum64(x) * (1.f / 64.f);
  const float df2 = x - m2;
  const float v2 = wsum64(df2 * df2) * (1.f / 64.f);
  out[row * ND + t] = df2 * rsqrtf(v2 + 1e-5f) * g2[t] + be2[t];
}

extern "C" void kernel_launch(void* const* d_in, const int* in_sizes, int n_in,
                              void* d_out, int out_size, void* d_ws, size_t ws_size,
                              hipStream_t stream) {
  const float* h   = (const float*)d_in[0];
  // d_in[1] = p (unused by the reference)
  const float* e   = (const float*)d_in[2];
  const float* kRW = (const float*)d_in[3];
  const float* Wq  = (const float*)d_in[4];
  const float* Wk  = (const float*)d_in[5];
  const float* We  = (const float*)d_in[6];
  const float* Wv  = (const float*)d_in[7];
  const float* Wo  = (const float*)d_in[8];
  const float* bo  = (const float*)d_in[9];
  const float* g1  = (const float*)d_in[10];
  const float* be1 = (const float*)d_in[11];
  const float* W1  = (const float*)d_in[12];
  const float* b1  = (const float*)d_in[13];
  const float* W2  = (const float*)d_in[14];
  const float* b2  = (const float*)d_in[15];
  const float* g2  = (const float*)d_in[16];
  const float* be2 = (const float*)d_in[17];
  float* out = (float*)d_out;

  float* Q = (float*)d_ws;                 // 3 * 1 MB scratch in d_ws
  float* K = Q + (size_t)NB * NN * ND;
  float* V = K + (size_t)NB * NN * ND;

  qkv_kernel<<<NB * NN, 64, 0, stream>>>(h, Wq, Wk, Wv, Q, K, V);
  fused_kernel<<<NB * NN, 256, 0, stream>>>(h, e, kRW, We, Wo, bo, g1, be1,
                                            W1, b1, W2, b2, g2, be2, Q, K, V, out);
}

// Round 3
// 261.746 us; speedup vs baseline: 1.0861x; 1.0861x over previous
//
#include <hip/hip_runtime.h>

// GraphiT-GT layer, fused. B=32, N=128, D=64, H=8, DH=8.
// R2: e fragments loaded global->register directly (no LDS staging, no
// conflicts); WeT precomputed once in bf16 (qkv grid +1 block); epilogue
// parallelized across all 4 waves.

#define NB 32
#define NN 128
#define ND 64

typedef __attribute__((ext_vector_type(8))) __bf16 bf16x8;
typedef __attribute__((ext_vector_type(8))) unsigned short u16x8;
typedef __attribute__((ext_vector_type(4))) float f32x4;

static __device__ __forceinline__ unsigned short f2bf(float x) {
  unsigned u = __float_as_uint(x);
  u += 0x7fffu + ((u >> 16) & 1u);   // RNE
  return (unsigned short)(u >> 16);
}

// v + dpp_perm(v): VALU-pipe cross-lane add
#define DPP_ADD(v, ctrl) \
  ((v) + __int_as_float(__builtin_amdgcn_update_dpp(0, __float_as_int(v), (ctrl), 0xf, 0xf, true)))

static __device__ __forceinline__ float wsum64(float v) {
  v += __shfl_xor(v, 1, 64);
  v += __shfl_xor(v, 2, 64);
  v += __shfl_xor(v, 4, 64);
  v += __shfl_xor(v, 8, 64);
  v += __shfl_xor(v, 16, 64);
  v += __shfl_xor(v, 32, 64);
  return v;
}

__global__ __launch_bounds__(64) void qkv_kernel(
    const float* __restrict__ h, const float* __restrict__ Wq,
    const float* __restrict__ Wk, const float* __restrict__ Wv,
    const float* __restrict__ We,
    float* __restrict__ Q, float* __restrict__ K, float* __restrict__ V,
    unsigned short* __restrict__ WeT) {
  if (blockIdx.x == NB * NN) {
    // one block: WeT_bf16[n*64+k] = bf16(We[k*64+n]); thread t = n
    const int t = threadIdx.x;
#pragma unroll
    for (int k0 = 0; k0 < ND; k0 += 8) {
      u16x8 u;
#pragma unroll
      for (int j = 0; j < 8; ++j) u[j] = f2bf(We[(k0 + j) * ND + t]);
      *(u16x8*)(&WeT[t * ND + k0]) = u;
    }
    return;
  }
  const int r = blockIdx.x;
  const int t = threadIdx.x;
  __shared__ float hrow[ND];
  hrow[t] = h[(size_t)r * ND + t];
  __syncthreads();
  float q = 0.f, k = 0.f, v = 0.f;
#pragma unroll 8
  for (int d = 0; d < ND; ++d) {
    const float hv = hrow[d];
    q = fmaf(hv, Wq[d * ND + t], q);
    k = fmaf(hv, Wk[d * ND + t], k);
    v = fmaf(hv, Wv[d * ND + t], v);
  }
  Q[(size_t)r * ND + t] = q;
  K[(size_t)r * ND + t] = k * 0.35355339059327373f;  // DH^-0.5 folded into K
  V[(size_t)r * ND + t] = v;
}

__global__ __launch_bounds__(256, 4) void fused_kernel(
    const float* __restrict__ h, const float* __restrict__ e,
    const float* __restrict__ kRW,
    const float* __restrict__ Wo, const float* __restrict__ bo,
    const float* __restrict__ g1, const float* __restrict__ be1,
    const float* __restrict__ W1, const float* __restrict__ b1,
    const float* __restrict__ W2, const float* __restrict__ b2,
    const float* __restrict__ g2, const float* __restrict__ be2,
    const float* __restrict__ Q, const float* __restrict__ K,
    const float* __restrict__ V, const unsigned short* __restrict__ WeT,
    float* __restrict__ out) {
  const int blk = blockIdx.x;
  const int b = blk >> 7;
  const int i = blk & 127;
  const int tid = threadIdx.x;
  const int w = tid >> 6;       // wave 0..3
  const int L = tid & 63;       // lane
  const int quad = L >> 4;
  const int lrow = L & 15;

  __shared__ float S_lds[NN * 9];     // S[j][h], pad 8->9
  __shared__ float krw_lds[NN];
  __shared__ float q_lds[ND];
  __shared__ float partN[4 * ND];     // reused as O-proj / FFN2 partials
  __shared__ float partD[4 * ND];     // reused as FFN1 partials
  __shared__ float attn_lds[ND];
  __shared__ float n1_lds[ND];
  __shared__ float ff_lds[2 * ND];

  const size_t row = (size_t)b * NN + i;
  const float* e_bi = e + row * (NN * ND);
  const size_t kvbase = (size_t)b * NN * ND;

  // small stagings (barrier deferred until after MFMA — MFMA has no LDS dep)
  if (tid < NN) krw_lds[tid] = kRW[row * NN + tid];
  if (tid < ND) q_lds[tid] = Q[row * ND + tid];

  // ---- A fragments: e rows straight from global (lane = 8 contiguous d) ----
  bf16x8 a_frag[2][2];
#pragma unroll
  for (int mr = 0; mr < 2; ++mr) {
    const int jrow = (w * 2 + mr) * 16 + lrow;
#pragma unroll
    for (int ks = 0; ks < 2; ++ks) {
      const float* p = e_bi + jrow * ND + ks * 32 + quad * 8;
      const float4 v0 = *(const float4*)(p);
      const float4 v1 = *(const float4*)(p + 4);
      u16x8 u;
      u[0] = f2bf(v0.x); u[1] = f2bf(v0.y); u[2] = f2bf(v0.z); u[3] = f2bf(v0.w);
      u[4] = f2bf(v1.x); u[5] = f2bf(v1.y); u[6] = f2bf(v1.z); u[7] = f2bf(v1.w);
      a_frag[mr][ks] = __builtin_bit_cast(bf16x8, u);
    }
  }
  // ---- B fragments: WeT bf16 straight from global (L2-hot, 8 KB total) ----
  bf16x8 b_frag[2][4];
#pragma unroll
  for (int ks = 0; ks < 2; ++ks)
#pragma unroll
    for (int n0 = 0; n0 < 4; ++n0)
      b_frag[ks][n0] = __builtin_bit_cast(
          bf16x8, *(const u16x8*)(&WeT[(n0 * 16 + lrow) * ND + ks * 32 + quad * 8]));

  // ---- MFMA: E[128x64] = e @ We; wave w owns j-rows [32w, 32w+32) ----
  f32x4 acc[2][4];
#pragma unroll
  for (int mr = 0; mr < 2; ++mr)
#pragma unroll
    for (int n0 = 0; n0 < 4; ++n0) acc[mr][n0] = (f32x4){0.f, 0.f, 0.f, 0.f};
#pragma unroll
  for (int mr = 0; mr < 2; ++mr)
#pragma unroll
    for (int ks = 0; ks < 2; ++ks)
#pragma unroll
      for (int n0 = 0; n0 < 4; ++n0)
        acc[mr][n0] = __builtin_amdgcn_mfma_f32_16x16x32_bf16(
            a_frag[mr][ks], b_frag[ks][n0], acc[mr][n0], 0, 0, 0);

  __syncthreads();  // covers krw_lds / q_lds staging

  // ---- scores: s[h,j] = exp(clip(sum_{d in h} E[j,d]*Q[i,d]*K[j,d]))*kRW[j] ----
  // C layout: col d = n0*16+lrow, row j = m0*16+quad*4+reg. 8-lane DPP reduce.
#pragma unroll
  for (int mr = 0; mr < 2; ++mr) {
    const int m0 = w * 2 + mr;
#pragma unroll
    for (int n0 = 0; n0 < 4; ++n0) {
      const int dout = n0 * 16 + lrow;
      const int hh = dout >> 3;
      const float qv = q_lds[dout];
      float sv[4];
#pragma unroll
      for (int reg = 0; reg < 4; ++reg) {
        const int j = m0 * 16 + quad * 4 + reg;
        const float kv = K[kvbase + (size_t)j * ND + dout];
        float tv = acc[mr][n0][reg] * qv * kv;
        tv = DPP_ADD(tv, 0xB1);   // quad_perm xor1
        tv = DPP_ADD(tv, 0x4E);   // quad_perm xor2
        tv = DPP_ADD(tv, 0x141);  // row_half_mirror (xor4)
        sv[reg] = __expf(fminf(fmaxf(tv, -5.f), 5.f)) * krw_lds[j];
      }
      if ((L & 7) == 0) {
#pragma unroll
        for (int reg = 0; reg < 4; ++reg)
          S_lds[(m0 * 16 + quad * 4 + reg) * 9 + hh] = sv[reg];
      }
    }
  }
  __syncthreads();

  // ---- attn numerator/denominator: wave w sums its 32 j's ----
  {
    float nump = 0.f, denp = 0.f;
#pragma unroll 4
    for (int jj = 0; jj < 32; ++jj) {
      const int j = w * 32 + jj;
      const float s = S_lds[j * 9 + (L >> 3)];
      const float v = V[kvbase + (size_t)j * ND + L];
      nump = fmaf(s, v, nump);
      denp += s;
    }
    partN[w * ND + L] = nump;
    partD[w * ND + L] = denp;
  }
  __syncthreads();

  if (tid < ND) {
    const float num = partN[tid] + partN[64 + tid] + partN[128 + tid] + partN[192 + tid];
    const float den = partD[tid] + partD[64 + tid] + partD[128 + tid] + partD[192 + tid];
    attn_lds[tid] = num / fmaxf(den, 1e-6f);
  }
  __syncthreads();

  // ---- O-proj: 4 waves x 16 input-channels each ----
  {
    float po = 0.f;
#pragma unroll
    for (int dd = 0; dd < 16; ++dd) {
      const int d = w * 16 + dd;
      po = fmaf(attn_lds[d], Wo[d * ND + L], po);
    }
    partN[w * ND + L] = po;
  }
  __syncthreads();
  if (tid < ND) {
    const float o = bo[tid] + partN[tid] + partN[64 + tid] + partN[128 + tid] + partN[192 + tid];
    const float h1 = h[row * ND + tid] + o;
    const float m1 = wsum64(h1) * (1.f / 64.f);
    const float df1 = h1 - m1;
    const float v1 = wsum64(df1 * df1) * (1.f / 64.f);
    n1_lds[tid] = df1 * rsqrtf(v1 + 1e-5f) * g1[tid] + be1[tid];
  }
  __syncthreads();

  // ---- FFN1: 256 threads = 128 outputs x 2 halves of the d-sum ----
  {
    const int ch = tid & 127;
    const int half = tid >> 7;
    float a = 0.f;
#pragma unroll
    for (int dd = 0; dd < 32; ++dd) {
      const int d = half * 32 + dd;
      a = fmaf(n1_lds[d], W1[d * 128 + ch], a);
    }
    partD[half * 128 + ch] = a;
  }
  __syncthreads();
  if (tid < 128) ff_lds[tid] = fmaxf(b1[tid] + partD[tid] + partD[128 + tid], 0.f);
  __syncthreads();

  // ---- FFN2: 256 threads = 64 outputs x 4 quarters of the u-sum ----
  {
    const int ch = tid & 63;
    const int q = tid >> 6;
    float a = 0.f;
#pragma unroll
    for (int uu = 0; uu < 32; ++uu) {
      const int u = q * 32 + uu;
      a = fmaf(ff_lds[u], W2[u * ND + ch], a);
    }
    partN[q * ND + ch] = a;
  }
  __syncthreads();
  if (tid < ND) {
    const float x = n1_lds[tid] + b2[tid] +
                    partN[tid] + partN[64 + tid] + partN[128 + tid] + partN[192 + tid];
    const float m2 = wsum64(x) * (1.f / 64.f);
    const float df2 = x - m2;
    const float v2 = wsum64(df2 * df2) * (1.f / 64.f);
    out[row * ND + tid] = df2 * rsqrtf(v2 + 1e-5f) * g2[tid] + be2[tid];
  }
}

extern "C" void kernel_launch(void* const* d_in, const int* in_sizes, int n_in,
                              void* d_out, int out_size, void* d_ws, size_t ws_size,
                              hipStream_t stream) {
  const float* h   = (const float*)d_in[0];
  const float* e   = (const float*)d_in[2];
  const float* kRW = (const float*)d_in[3];
  const float* Wq  = (const float*)d_in[4];
  const float* Wk  = (const float*)d_in[5];
  const float* We  = (const float*)d_in[6];
  const float* Wv  = (const float*)d_in[7];
  const float* Wo  = (const float*)d_in[8];
  const float* bo  = (const float*)d_in[9];
  const float* g1  = (const float*)d_in[10];
  const float* be1 = (const float*)d_in[11];
  const float* W1  = (const float*)d_in[12];
  const float* b1  = (const float*)d_in[13];
  const float* W2  = (const float*)d_in[14];
  const float* b2  = (const float*)d_in[15];
  const float* g2  = (const float*)d_in[16];
  const float* be2 = (const float*)d_in[17];
  float* out = (float*)d_out;

  float* Q = (float*)d_ws;
  float* K = Q + (size_t)NB * NN * ND;
  float* V = K + (size_t)NB * NN * ND;
  unsigned short* WeT = (unsigned short*)(V + (size_t)NB * NN * ND);

  qkv_kernel<<<NB * NN + 1, 64, 0, stream>>>(h, Wq, Wk, Wv, We, Q, K, V, WeT);
  fused_kernel<<<NB * NN, 256, 0, stream>>>(h, e, kRW, Wo, bo, g1, be1,
                                            W1, b1, W2, b2, g2, be2, Q, K, V, WeT, out);
}

// Round 4
// 258.000 us; speedup vs baseline: 1.1019x; 1.0145x over previous
//
#include <hip/hip_runtime.h>

// GraphiT-GT layer, fused. B=32, N=128, D=64, H=8, DH=8.
// R4: single-wave blocks (64 thr, 4096 blocks -> 16 independent chains/CU at
// <=128 VGPR). Per-16-row m-tile: MFMA acc[4] consumed immediately by score
// epilogue (register reuse). K stored transposed (KT[b][d][j]) so score K
// loads are dwordx4. Barriers are now intra-wave (near-free).

#define NB 32
#define NN 128
#define ND 64

typedef __attribute__((ext_vector_type(8))) __bf16 bf16x8;
typedef __attribute__((ext_vector_type(8))) unsigned short u16x8;
typedef __attribute__((ext_vector_type(4))) float f32x4;

static __device__ __forceinline__ unsigned short f2bf(float x) {
  unsigned u = __float_as_uint(x);
  u += 0x7fffu + ((u >> 16) & 1u);   // RNE
  return (unsigned short)(u >> 16);
}

// v + dpp_perm(v): VALU-pipe cross-lane add
#define DPP_ADD(v, ctrl) \
  ((v) + __int_as_float(__builtin_amdgcn_update_dpp(0, __float_as_int(v), (ctrl), 0xf, 0xf, true)))

static __device__ __forceinline__ float wsum64(float v) {
  v += __shfl_xor(v, 1, 64);
  v += __shfl_xor(v, 2, 64);
  v += __shfl_xor(v, 4, 64);
  v += __shfl_xor(v, 8, 64);
  v += __shfl_xor(v, 16, 64);
  v += __shfl_xor(v, 32, 64);
  return v;
}

__global__ __launch_bounds__(64) void qkv_kernel(
    const float* __restrict__ h, const float* __restrict__ Wq,
    const float* __restrict__ Wk, const float* __restrict__ Wv,
    const float* __restrict__ We,
    float* __restrict__ Q, float* __restrict__ KT, float* __restrict__ V,
    unsigned short* __restrict__ WeT) {
  if (blockIdx.x == NB * NN) {
    // one block: WeT_bf16[n*64+k] = bf16(We[k*64+n]); thread t = n
    const int t = threadIdx.x;
#pragma unroll
    for (int k0 = 0; k0 < ND; k0 += 8) {
      u16x8 u;
#pragma unroll
      for (int j = 0; j < 8; ++j) u[j] = f2bf(We[(k0 + j) * ND + t]);
      *(u16x8*)(&WeT[t * ND + k0]) = u;
    }
    return;
  }
  const int r = blockIdx.x;       // r = b*128 + n
  const int t = threadIdx.x;
  __shared__ float hrow[ND];
  hrow[t] = h[(size_t)r * ND + t];
  __syncthreads();
  float q = 0.f, k = 0.f, v = 0.f;
#pragma unroll 8
  for (int d = 0; d < ND; ++d) {
    const float hv = hrow[d];
    q = fmaf(hv, Wq[d * ND + t], q);
    k = fmaf(hv, Wk[d * ND + t], k);
    v = fmaf(hv, Wv[d * ND + t], v);
  }
  Q[(size_t)r * ND + t] = q;
  // K transposed: KT[b][d][j], DH^-0.5 folded in
  KT[((size_t)(r >> 7) * ND + t) * NN + (r & 127)] = k * 0.35355339059327373f;
  V[(size_t)r * ND + t] = v;
}

__global__ __launch_bounds__(64, 4) void fused_kernel(
    const float* __restrict__ h, const float* __restrict__ e,
    const float* __restrict__ kRW,
    const float* __restrict__ Wo, const float* __restrict__ bo,
    const float* __restrict__ g1, const float* __restrict__ be1,
    const float* __restrict__ W1, const float* __restrict__ b1,
    const float* __restrict__ W2, const float* __restrict__ b2,
    const float* __restrict__ g2, const float* __restrict__ be2,
    const float* __restrict__ Q, const float* __restrict__ KT,
    const float* __restrict__ V, const unsigned short* __restrict__ WeT,
    float* __restrict__ out) {
  const int blk = blockIdx.x;
  const int b = blk >> 7;
  const int i = blk & 127;
  const int L = threadIdx.x;    // single wave
  const int quad = L >> 4;
  const int lrow = L & 15;
  const int h8 = L >> 3;

  __shared__ float S_lds[NN * 9];   // S[j][h], pad 8->9
  __shared__ float krw_lds[NN];
  __shared__ float q_lds[ND];
  __shared__ float attn_lds[ND];
  __shared__ float n1_lds[ND];
  __shared__ float ff_lds[2 * ND];

  const size_t row = (size_t)b * NN + i;
  const float* e_bi = e + row * (NN * ND);
  const size_t kvbase = (size_t)b * NN * ND;
  const size_t ktbase = (size_t)b * ND * NN;

  q_lds[L] = Q[row * ND + L];
  krw_lds[L] = kRW[row * NN + L];
  krw_lds[64 + L] = kRW[row * NN + 64 + L];

  // ---- B fragments: WeT bf16 from global (L2-hot, 8 KB total) ----
  bf16x8 bfr[2][4];
#pragma unroll
  for (int ks = 0; ks < 2; ++ks)
#pragma unroll
    for (int n0 = 0; n0 < 4; ++n0)
      bfr[ks][n0] = __builtin_bit_cast(
          bf16x8, *(const u16x8*)(&WeT[(n0 * 16 + lrow) * ND + ks * 32 + quad * 8]));

  __syncthreads();  // single wave: cheap; orders q/krw staging

  // ---- per 16-row m-tile: MFMA -> score epilogue (acc regs reused) ----
#pragma unroll 2
  for (int mr = 0; mr < 8; ++mr) {
    const float* p = e_bi + (mr * 16 + lrow) * ND;
    bf16x8 afr[2];
#pragma unroll
    for (int ks = 0; ks < 2; ++ks) {
      const float4 v0 = *(const float4*)(p + ks * 32 + quad * 8);
      const float4 v1 = *(const float4*)(p + ks * 32 + quad * 8 + 4);
      u16x8 u;
      u[0] = f2bf(v0.x); u[1] = f2bf(v0.y); u[2] = f2bf(v0.z); u[3] = f2bf(v0.w);
      u[4] = f2bf(v1.x); u[5] = f2bf(v1.y); u[6] = f2bf(v1.z); u[7] = f2bf(v1.w);
      afr[ks] = __builtin_bit_cast(bf16x8, u);
    }
    f32x4 acc[4];
#pragma unroll
    for (int n0 = 0; n0 < 4; ++n0) acc[n0] = (f32x4){0.f, 0.f, 0.f, 0.f};
#pragma unroll
    for (int ks = 0; ks < 2; ++ks)
#pragma unroll
      for (int n0 = 0; n0 < 4; ++n0)
        acc[n0] = __builtin_amdgcn_mfma_f32_16x16x32_bf16(afr[ks], bfr[ks][n0], acc[n0], 0, 0, 0);

    // scores for j in [mr*16, mr*16+16): C layout col d = n0*16+lrow,
    // row j = mr*16 + quad*4 + reg. 8-lane DPP head-reduce.
#pragma unroll
    for (int n0 = 0; n0 < 4; ++n0) {
      const int dout = n0 * 16 + lrow;
      const float qv = q_lds[dout];
      const float4 kv = *(const float4*)(&KT[ktbase + (size_t)dout * NN + mr * 16 + quad * 4]);
      const float* kvp = (const float*)&kv;
      float sv[4];
#pragma unroll
      for (int reg = 0; reg < 4; ++reg) {
        float tv = acc[n0][reg] * qv * kvp[reg];
        tv = DPP_ADD(tv, 0xB1);   // quad_perm xor1
        tv = DPP_ADD(tv, 0x4E);   // quad_perm xor2
        tv = DPP_ADD(tv, 0x141);  // row_half_mirror (completes 8-group)
        sv[reg] = __expf(fminf(fmaxf(tv, -5.f), 5.f)) * krw_lds[mr * 16 + quad * 4 + reg];
      }
      if ((L & 7) == 0) {
#pragma unroll
        for (int reg = 0; reg < 4; ++reg)
          S_lds[(mr * 16 + quad * 4 + reg) * 9 + (dout >> 3)] = sv[reg];
      }
    }
  }
  __syncthreads();

  // ---- attn: lane L = output channel, head h8 = L>>3 ----
  float nump = 0.f, denp = 0.f;
#pragma unroll 8
  for (int j = 0; j < NN; ++j) {
    const float s = S_lds[j * 9 + h8];
    const float v = V[kvbase + (size_t)j * ND + L];
    nump = fmaf(s, v, nump);
    denp += s;
  }
  attn_lds[L] = nump / fmaxf(denp, 1e-6f);
  __syncthreads();

  // ---- O-proj + residual + LN1 ----
  float o = bo[L];
#pragma unroll 8
  for (int d = 0; d < ND; ++d) o = fmaf(attn_lds[d], Wo[d * ND + L], o);
  const float h1v = h[row * ND + L] + o;
  const float m1 = wsum64(h1v) * (1.f / 64.f);
  const float df1 = h1v - m1;
  const float v1 = wsum64(df1 * df1) * (1.f / 64.f);
  const float n1 = df1 * rsqrtf(v1 + 1e-5f) * g1[L] + be1[L];
  n1_lds[L] = n1;
  __syncthreads();

  // ---- FFN1 (lane handles outputs L and L+64) ----
  float a0 = b1[L], a1 = b1[64 + L];
#pragma unroll 8
  for (int d = 0; d < ND; ++d) {
    const float nv = n1_lds[d];
    a0 = fmaf(nv, W1[d * 128 + L], a0);
    a1 = fmaf(nv, W1[d * 128 + 64 + L], a1);
  }
  ff_lds[L] = fmaxf(a0, 0.f);
  ff_lds[64 + L] = fmaxf(a1, 0.f);
  __syncthreads();

  // ---- FFN2 + residual + LN2 ----
  float o2 = b2[L];
#pragma unroll 8
  for (int u = 0; u < 128; ++u) o2 = fmaf(ff_lds[u], W2[u * ND + L], o2);
  const float x = n1 + o2;
  const float m2 = wsum64(x) * (1.f / 64.f);
  const float df2 = x - m2;
  const float v2 = wsum64(df2 * df2) * (1.f / 64.f);
  out[row * ND + L] = df2 * rsqrtf(v2 + 1e-5f) * g2[L] + be2[L];
}

extern "C" void kernel_launch(void* const* d_in, const int* in_sizes, int n_in,
                              void* d_out, int out_size, void* d_ws, size_t ws_size,
                              hipStream_t stream) {
  const float* h   = (const float*)d_in[0];
  const float* e   = (const float*)d_in[2];
  const float* kRW = (const float*)d_in[3];
  const float* Wq  = (const float*)d_in[4];
  const float* Wk  = (const float*)d_in[5];
  const float* We  = (const float*)d_in[6];
  const float* Wv  = (const float*)d_in[7];
  const float* Wo  = (const float*)d_in[8];
  const float* bo  = (const float*)d_in[9];
  const float* g1  = (const float*)d_in[10];
  const float* be1 = (const float*)d_in[11];
  const float* W1  = (const float*)d_in[12];
  const float* b1  = (const float*)d_in[13];
  const float* W2  = (const float*)d_in[14];
  const float* b2  = (const float*)d_in[15];
  const float* g2  = (const float*)d_in[16];
  const float* be2 = (const float*)d_in[17];
  float* out = (float*)d_out;

  float* Q  = (float*)d_ws;
  float* KT = Q + (size_t)NB * NN * ND;
  float* V  = KT + (size_t)NB * NN * ND;
  unsigned short* WeT = (unsigned short*)(V + (size_t)NB * NN * ND);

  qkv_kernel<<<NB * NN + 1, 64, 0, stream>>>(h, Wq, Wk, Wv, We, Q, KT, V, WeT);
  fused_kernel<<<NB * NN, 64, 0, stream>>>(h, e, kRW, Wo, bo, g1, be1,
                                           W1, b1, W2, b2, g2, be2, Q, KT, V, WeT, out);
}

// Round 5
// 256.479 us; speedup vs baseline: 1.1084x; 1.0059x over previous
//
#include <hip/hip_runtime.h>

// GraphiT-GT layer, fused. B=32, N=128, D=64, H=8, DH=8.
// R5: latency-bound fix — deep MLP everywhere.
//  * Phase 1: e-tiles AND KT-tiles double-buffered 2-deep; issue order chosen
//    so every vmcnt wait targets a 2-iteration-old load (no young drains).
//  * Phases 2-5: all matvecs restructured as coalesced dwordx4 row-streams
//    (lane = (row-group, col-quad)) + shfl_xor partial reduction, replacing
//    ~450 dependent scalar loads per lane with ~112 independent vector loads.

#define NB 32
#define NN 128
#define ND 64

typedef __attribute__((ext_vector_type(8))) __bf16 bf16x8;
typedef __attribute__((ext_vector_type(8))) unsigned short u16x8;
typedef __attribute__((ext_vector_type(4))) float f32x4;

static __device__ __forceinline__ unsigned short f2bf(float x) {
  unsigned u = __float_as_uint(x);
  u += 0x7fffu + ((u >> 16) & 1u);   // RNE
  return (unsigned short)(u >> 16);
}

#define DPP_ADD(v, ctrl) \
  ((v) + __int_as_float(__builtin_amdgcn_update_dpp(0, __float_as_int(v), (ctrl), 0xf, 0xf, true)))

static __device__ __forceinline__ float wsum64(float v) {
  v += __shfl_xor(v, 1, 64);
  v += __shfl_xor(v, 2, 64);
  v += __shfl_xor(v, 4, 64);
  v += __shfl_xor(v, 8, 64);
  v += __shfl_xor(v, 16, 64);
  v += __shfl_xor(v, 32, 64);
  return v;
}

static __device__ __forceinline__ float4 xor_add4(float4 a, int m) {
  a.x += __shfl_xor(a.x, m, 64);
  a.y += __shfl_xor(a.y, m, 64);
  a.z += __shfl_xor(a.z, m, 64);
  a.w += __shfl_xor(a.w, m, 64);
  return a;
}

__global__ __launch_bounds__(64) void qkv_kernel(
    const float* __restrict__ h, const float* __restrict__ Wq,
    const float* __restrict__ Wk, const float* __restrict__ Wv,
    const float* __restrict__ We,
    float* __restrict__ Q, float* __restrict__ KT, float* __restrict__ V,
    unsigned short* __restrict__ WeT) {
  if (blockIdx.x == NB * NN) {
    const int t = threadIdx.x;
#pragma unroll
    for (int k0 = 0; k0 < ND; k0 += 8) {
      u16x8 u;
#pragma unroll
      for (int j = 0; j < 8; ++j) u[j] = f2bf(We[(k0 + j) * ND + t]);
      *(u16x8*)(&WeT[t * ND + k0]) = u;
    }
    return;
  }
  const int r = blockIdx.x;       // r = b*128 + n
  const int t = threadIdx.x;
  __shared__ float hrow[ND];
  hrow[t] = h[(size_t)r * ND + t];
  __syncthreads();
  float q = 0.f, k = 0.f, v = 0.f;
#pragma unroll 8
  for (int d = 0; d < ND; ++d) {
    const float hv = hrow[d];
    q = fmaf(hv, Wq[d * ND + t], q);
    k = fmaf(hv, Wk[d * ND + t], k);
    v = fmaf(hv, Wv[d * ND + t], v);
  }
  Q[(size_t)r * ND + t] = q;
  KT[((size_t)(r >> 7) * ND + t) * NN + (r & 127)] = k * 0.35355339059327373f;
  V[(size_t)r * ND + t] = v;
}

__global__ __launch_bounds__(64) void fused_kernel(
    const float* __restrict__ h, const float* __restrict__ e,
    const float* __restrict__ kRW,
    const float* __restrict__ Wo, const float* __restrict__ bo,
    const float* __restrict__ g1, const float* __restrict__ be1,
    const float* __restrict__ W1, const float* __restrict__ b1,
    const float* __restrict__ W2, const float* __restrict__ b2,
    const float* __restrict__ g2, const float* __restrict__ be2,
    const float* __restrict__ Q, const float* __restrict__ KT,
    const float* __restrict__ V, const unsigned short* __restrict__ WeT,
    float* __restrict__ out) {
  const int blk = blockIdx.x;
  const int b = blk >> 7;
  const int i = blk & 127;
  const int L = threadIdx.x;    // single wave
  const int quad = L >> 4;
  const int c4 = L & 15;        // lrow / float4-column
  const int lrow = c4;

  __shared__ float S_lds[NN * 9];   // S[j][h], pad 8->9
  __shared__ float krw_lds[NN];
  __shared__ float q_lds[ND];
  __shared__ float attn_lds[ND];
  __shared__ float n1_lds[ND];
  __shared__ float ff_lds[2 * ND];

  const size_t row = (size_t)b * NN + i;
  const float* e_bi = e + row * (NN * ND);
  const size_t kvbase = (size_t)b * NN * ND;
  const size_t ktbase = (size_t)b * ND * NN;

  // ---- staging + prefetch (all drained by the single prologue barrier) ----
  q_lds[L] = Q[row * ND + L];
  krw_lds[L] = kRW[row * NN + L];
  krw_lds[64 + L] = kRW[row * NN + 64 + L];

  bf16x8 bfr[2][4];
#pragma unroll
  for (int ks = 0; ks < 2; ++ks)
#pragma unroll
    for (int n0 = 0; n0 < 4; ++n0)
      bfr[ks][n0] = __builtin_bit_cast(
          bf16x8, *(const u16x8*)(&WeT[(n0 * 16 + lrow) * ND + ks * 32 + quad * 8]));

  float4 eb[2][4], ktb[2][4];
#define LD_E(mr, dst)                                              \
  {                                                                \
    const float* p_ = e_bi + ((mr) * 16 + lrow) * ND + quad * 8;   \
    (dst)[0] = *(const float4*)(p_);                               \
    (dst)[1] = *(const float4*)(p_ + 4);                           \
    (dst)[2] = *(const float4*)(p_ + 32);                          \
    (dst)[3] = *(const float4*)(p_ + 36);                          \
  }
#define LD_KT(mr, dst)                                                          \
  {                                                                             \
    _Pragma("unroll")                                                           \
    for (int n0_ = 0; n0_ < 4; ++n0_)                                           \
      (dst)[n0_] = *(const float4*)(&KT[ktbase + (size_t)(n0_ * 16 + lrow) * NN \
                                        + (mr) * 16 + quad * 4]);               \
  }
  LD_E(0, eb[0]); LD_KT(0, ktb[0]);
  LD_E(1, eb[1]); LD_KT(1, ktb[1]);
  __syncthreads();

  float qv[4];
#pragma unroll
  for (int n0 = 0; n0 < 4; ++n0) qv[n0] = q_lds[n0 * 16 + lrow];

  // ---- phase 1: per 16-row m-tile MFMA + score epilogue, 2-deep pipeline ----
  // Issue order per iter: [wait e(m), cvt] -> issue e(m+2) -> MFMA ->
  // [wait kt(m), epilogue] -> issue kt(m+2). In-order vmcnt: both waits
  // target 2-iteration-old loads; no young prefetch is drained.
#pragma unroll
  for (int mr = 0; mr < 8; ++mr) {
    const int cur = mr & 1;
    bf16x8 afr[2];
#pragma unroll
    for (int ks = 0; ks < 2; ++ks) {
      const float4 v0 = eb[cur][ks * 2], v1 = eb[cur][ks * 2 + 1];
      u16x8 u;
      u[0] = f2bf(v0.x); u[1] = f2bf(v0.y); u[2] = f2bf(v0.z); u[3] = f2bf(v0.w);
      u[4] = f2bf(v1.x); u[5] = f2bf(v1.y); u[6] = f2bf(v1.z); u[7] = f2bf(v1.w);
      afr[ks] = __builtin_bit_cast(bf16x8, u);
    }
    if (mr < 6) LD_E(mr + 2, eb[cur]);

    f32x4 acc[4];
#pragma unroll
    for (int n0 = 0; n0 < 4; ++n0) acc[n0] = (f32x4){0.f, 0.f, 0.f, 0.f};
#pragma unroll
    for (int ks = 0; ks < 2; ++ks)
#pragma unroll
      for (int n0 = 0; n0 < 4; ++n0)
        acc[n0] = __builtin_amdgcn_mfma_f32_16x16x32_bf16(afr[ks], bfr[ks][n0], acc[n0], 0, 0, 0);

    const float4 krw4 = *(const float4*)(&krw_lds[mr * 16 + quad * 4]);
    const float* krwp = (const float*)&krw4;
#pragma unroll
    for (int n0 = 0; n0 < 4; ++n0) {
      const float qn = qv[n0];
      const float* kvp = (const float*)&ktb[cur][n0];
      float sv[4];
#pragma unroll
      for (int reg = 0; reg < 4; ++reg) {
        float tv = acc[n0][reg] * qn * kvp[reg];
        tv = DPP_ADD(tv, 0xB1);   // quad_perm xor1
        tv = DPP_ADD(tv, 0x4E);   // quad_perm xor2
        tv = DPP_ADD(tv, 0x141);  // row_half_mirror (completes 8-lane head)
        sv[reg] = __expf(fminf(fmaxf(tv, -5.f), 5.f)) * krwp[reg];
      }
      if ((L & 7) == 0) {
        const int hh = n0 * 2 + ((L >> 3) & 1);
#pragma unroll
        for (int reg = 0; reg < 4; ++reg)
          S_lds[(mr * 16 + quad * 4 + reg) * 9 + hh] = sv[reg];
      }
    }
    if (mr < 6) LD_KT(mr + 2, ktb[cur]);
  }
  __syncthreads();

  // ---- phase 2: attn = (S @ V) / rowsum(S); lane = (jj = L>>4, c4) ----
  // coalesced: per chunk the wave reads V rows 4t..4t+3 fully (1 KB).
  const int jj = L >> 4;
  const int hh2 = c4 >> 1;      // head of channels 4*c4..4*c4+3
  float4 an = make_float4(0.f, 0.f, 0.f, 0.f);
  float den = 0.f;
#pragma unroll 8
  for (int t = 0; t < 32; ++t) {
    const int j = t * 4 + jj;
    const float s = S_lds[j * 9 + hh2];
    const float4 v = *(const float4*)(&V[kvbase + (size_t)j * ND + c4 * 4]);
    an.x = fmaf(s, v.x, an.x);
    an.y = fmaf(s, v.y, an.y);
    an.z = fmaf(s, v.z, an.z);
    an.w = fmaf(s, v.w, an.w);
    den += s;
  }
  an = xor_add4(an, 16); an = xor_add4(an, 32);
  den += __shfl_xor(den, 16, 64); den += __shfl_xor(den, 32, 64);
  const float rden = 1.f / fmaxf(den, 1e-6f);
  if (L < 16)
    *(float4*)(&attn_lds[c4 * 4]) =
        make_float4(an.x * rden, an.y * rden, an.z * rden, an.w * rden);
  __syncthreads();

  // ---- phase 3: O-proj + residual + LN1; lane = (dd = L>>4, c4) ----
  float4 o4 = make_float4(0.f, 0.f, 0.f, 0.f);
#pragma unroll 4
  for (int t = 0; t < 16; ++t) {
    const int d = t * 4 + jj;
    const float a = attn_lds[d];
    const float4 wv = *(const float4*)(&Wo[d * ND + c4 * 4]);
    o4.x = fmaf(a, wv.x, o4.x);
    o4.y = fmaf(a, wv.y, o4.y);
    o4.z = fmaf(a, wv.z, o4.z);
    o4.w = fmaf(a, wv.w, o4.w);
  }
  o4 = xor_add4(o4, 16); o4 = xor_add4(o4, 32);
  const float4 bo4 = *(const float4*)(&bo[c4 * 4]);
  const float4 h4 = *(const float4*)(&h[row * ND + c4 * 4]);
  float4 h1;
  h1.x = h4.x + bo4.x + o4.x;
  h1.y = h4.y + bo4.y + o4.y;
  h1.z = h4.z + bo4.z + o4.z;
  h1.w = h4.w + bo4.w + o4.w;
  // each channel held by 4 lanes -> wsum64 counts 4x -> /256
  const float m1 = wsum64(h1.x + h1.y + h1.z + h1.w) * (1.f / 256.f);
  float4 df;
  df.x = h1.x - m1; df.y = h1.y - m1; df.z = h1.z - m1; df.w = h1.w - m1;
  const float v1 =
      wsum64(df.x * df.x + df.y * df.y + df.z * df.z + df.w * df.w) * (1.f / 256.f);
  const float r1 = rsqrtf(v1 + 1e-5f);
  const float4 g14 = *(const float4*)(&g1[c4 * 4]);
  const float4 be14 = *(const float4*)(&be1[c4 * 4]);
  float4 n14;
  n14.x = df.x * r1 * g14.x + be14.x;
  n14.y = df.y * r1 * g14.y + be14.y;
  n14.z = df.z * r1 * g14.z + be14.z;
  n14.w = df.w * r1 * g14.w + be14.w;
  if (L < 16) *(float4*)(&n1_lds[c4 * 4]) = n14;
  __syncthreads();

  // ---- phase 4: FFN1 + ReLU; lane = (dd2 = L>>5, c5 = L&31) ----
  const int dd2 = L >> 5;
  const int c5 = L & 31;
  float4 f4 = make_float4(0.f, 0.f, 0.f, 0.f);
#pragma unroll 8
  for (int t = 0; t < 32; ++t) {
    const int d = t * 2 + dd2;
    const float nv = n1_lds[d];
    const float4 wv = *(const float4*)(&W1[d * 128 + c5 * 4]);
    f4.x = fmaf(nv, wv.x, f4.x);
    f4.y = fmaf(nv, wv.y, f4.y);
    f4.z = fmaf(nv, wv.z, f4.z);
    f4.w = fmaf(nv, wv.w, f4.w);
  }
  f4 = xor_add4(f4, 32);
  const float4 b14 = *(const float4*)(&b1[c5 * 4]);
  if (L < 32)
    *(float4*)(&ff_lds[c5 * 4]) =
        make_float4(fmaxf(f4.x + b14.x, 0.f), fmaxf(f4.y + b14.y, 0.f),
                    fmaxf(f4.z + b14.z, 0.f), fmaxf(f4.w + b14.w, 0.f));
  __syncthreads();

  // ---- phase 5: FFN2 + residual + LN2; lane = (uu = L>>4, c4) ----
  float4 q4 = make_float4(0.f, 0.f, 0.f, 0.f);
#pragma unroll 8
  for (int t = 0; t < 32; ++t) {
    const int u = t * 4 + jj;
    const float fv = ff_lds[u];
    const float4 wv = *(const float4*)(&W2[u * ND + c4 * 4]);
    q4.x = fmaf(fv, wv.x, q4.x);
    q4.y = fmaf(fv, wv.y, q4.y);
    q4.z = fmaf(fv, wv.z, q4.z);
    q4.w = fmaf(fv, wv.w, q4.w);
  }
  q4 = xor_add4(q4, 16); q4 = xor_add4(q4, 32);
  const float4 b24 = *(const float4*)(&b2[c4 * 4]);
  float4 x4;
  x4.x = n14.x + b24.x + q4.x;
  x4.y = n14.y + b24.y + q4.y;
  x4.z = n14.z + b24.z + q4.z;
  x4.w = n14.w + b24.w + q4.w;
  const float m2 = wsum64(x4.x + x4.y + x4.z + x4.w) * (1.f / 256.f);
  float4 d2;
  d2.x = x4.x - m2; d2.y = x4.y - m2; d2.z = x4.z - m2; d2.w = x4.w - m2;
  const float v2 =
      wsum64(d2.x * d2.x + d2.y * d2.y + d2.z * d2.z + d2.w * d2.w) * (1.f / 256.f);
  const float r2 = rsqrtf(v2 + 1e-5f);
  const float4 g24 = *(const float4*)(&g2[c4 * 4]);
  const float4 be24 = *(const float4*)(&be2[c4 * 4]);
  if (L < 16)
    *(float4*)(&out[row * ND + c4 * 4]) =
        make_float4(d2.x * r2 * g24.x + be24.x, d2.y * r2 * g24.y + be24.y,
                    d2.z * r2 * g24.z + be24.z, d2.w * r2 * g24.w + be24.w);
}

extern "C" void kernel_launch(void* const* d_in, const int* in_sizes, int n_in,
                              void* d_out, int out_size, void* d_ws, size_t ws_size,
                              hipStream_t stream) {
  const float* h   = (const float*)d_in[0];
  const float* e   = (const float*)d_in[2];
  const float* kRW = (const float*)d_in[3];
  const float* Wq  = (const float*)d_in[4];
  const float* Wk  = (const float*)d_in[5];
  const float* We  = (const float*)d_in[6];
  const float* Wv  = (const float*)d_in[7];
  const float* Wo  = (const float*)d_in[8];
  const float* bo  = (const float*)d_in[9];
  const float* g1  = (const float*)d_in[10];
  const float* be1 = (const float*)d_in[11];
  const float* W1  = (const float*)d_in[12];
  const float* b1  = (const float*)d_in[13];
  const float* W2  = (const float*)d_in[14];
  const float* b2  = (const float*)d_in[15];
  const float* g2  = (const float*)d_in[16];
  const float* be2 = (const float*)d_in[17];
  float* out = (float*)d_out;

  float* Q  = (float*)d_ws;
  float* KT = Q + (size_t)NB * NN * ND;
  float* V  = KT + (size_t)NB * NN * ND;
  unsigned short* WeT = (unsigned short*)(V + (size_t)NB * NN * ND);

  qkv_kernel<<<NB * NN + 1, 64, 0, stream>>>(h, Wq, Wk, Wv, We, Q, KT, V, WeT);
  fused_kernel<<<NB * NN, 64, 0, stream>>>(h, e, kRW, Wo, bo, g1, be1,
                                           W1, b1, W2, b2, g2, be2, Q, KT, V, WeT, out);
}

// Round 6
// 249.560 us; speedup vs baseline: 1.1392x; 1.0277x over previous
//
#include <hip/hip_runtime.h>

// GraphiT-GT layer, fused. B=32, N=128, D=64, H=8, DH=8.
// R6: kill 16B-granular scattered VMEM (the L1/TA amplifier):
//  * block = 4 rows (grid 1024, 256 thr); wave w owns row i0+w.
//  * e-tile: coalesced 256-thread float4 stage -> bf16 LDS (stride 72,
//    16B-aligned rows; ds_read_b128 fragments are 2-way = free).
//  * K epilogue values: loaded ONCE into 32 regs (coalesced 4-CL scalar
//    loads), reused across all 4 rows.
//  * phases 2-5: per-wave private, coalesced row-streams, no barriers.

#define NB 32
#define NN 128
#define ND 64
#define G 4

typedef __attribute__((ext_vector_type(8))) __bf16 bf16x8;
typedef __attribute__((ext_vector_type(8))) unsigned short u16x8;
typedef __attribute__((ext_vector_type(4))) float f32x4;

static __device__ __forceinline__ unsigned short f2bf(float x) {
  unsigned u = __float_as_uint(x);
  u += 0x7fffu + ((u >> 16) & 1u);   // RNE
  return (unsigned short)(u >> 16);
}
static __device__ __forceinline__ float bf2f(unsigned short u) {
  return __uint_as_float(((unsigned)u) << 16);
}

#define DPP_ADD(v, ctrl) \
  ((v) + __int_as_float(__builtin_amdgcn_update_dpp(0, __float_as_int(v), (ctrl), 0xf, 0xf, true)))

static __device__ __forceinline__ float wsum64(float v) {
  v += __shfl_xor(v, 1, 64);
  v += __shfl_xor(v, 2, 64);
  v += __shfl_xor(v, 4, 64);
  v += __shfl_xor(v, 8, 64);
  v += __shfl_xor(v, 16, 64);
  v += __shfl_xor(v, 32, 64);
  return v;
}

static __device__ __forceinline__ float4 xor_add4(float4 a, int m) {
  a.x += __shfl_xor(a.x, m, 64);
  a.y += __shfl_xor(a.y, m, 64);
  a.z += __shfl_xor(a.z, m, 64);
  a.w += __shfl_xor(a.w, m, 64);
  return a;
}

__global__ __launch_bounds__(64) void qkv_kernel(
    const float* __restrict__ h, const float* __restrict__ Wq,
    const float* __restrict__ Wk, const float* __restrict__ Wv,
    const float* __restrict__ We,
    float* __restrict__ Q, float* __restrict__ K, float* __restrict__ V,
    unsigned short* __restrict__ WeT) {
  if (blockIdx.x == NB * NN) {
    const int t = threadIdx.x;
#pragma unroll
    for (int k0 = 0; k0 < ND; k0 += 8) {
      u16x8 u;
#pragma unroll
      for (int j = 0; j < 8; ++j) u[j] = f2bf(We[(k0 + j) * ND + t]);
      *(u16x8*)(&WeT[t * ND + k0]) = u;
    }
    return;
  }
  const int r = blockIdx.x;       // r = b*128 + n
  const int t = threadIdx.x;
  __shared__ float hrow[ND];
  hrow[t] = h[(size_t)r * ND + t];
  __syncthreads();
  float q = 0.f, k = 0.f, v = 0.f;
#pragma unroll 8
  for (int d = 0; d < ND; ++d) {
    const float hv = hrow[d];
    q = fmaf(hv, Wq[d * ND + t], q);
    k = fmaf(hv, Wk[d * ND + t], k);
    v = fmaf(hv, Wv[d * ND + t], v);
  }
  Q[(size_t)r * ND + t] = q;
  K[(size_t)r * ND + t] = k * 0.35355339059327373f;  // DH^-0.5 folded in
  V[(size_t)r * ND + t] = v;
}

__global__ __launch_bounds__(256, 4) void fused_kernel(
    const float* __restrict__ h, const float* __restrict__ e,
    const float* __restrict__ kRW,
    const float* __restrict__ Wo, const float* __restrict__ bo,
    const float* __restrict__ g1, const float* __restrict__ be1,
    const float* __restrict__ W1, const float* __restrict__ b1,
    const float* __restrict__ W2, const float* __restrict__ b2,
    const float* __restrict__ g2, const float* __restrict__ be2,
    const float* __restrict__ Q, const float* __restrict__ K,
    const float* __restrict__ V, const unsigned short* __restrict__ WeT,
    float* __restrict__ out) {
  const int blk = blockIdx.x;
  const int b = blk >> 5;
  const int i0 = (blk & 31) * G;
  const int tid = threadIdx.x;
  const int w = tid >> 6;       // wave 0..3 = row i0+w
  const int L = tid & 63;
  const int quad = L >> 4;
  const int lrow = L & 15;

  __shared__ __align__(16) unsigned short e_lds[NN * 72];   // bf16 tile, 18 KB
  __shared__ __align__(16) unsigned short S_lds[G * 8 * 136];  // [g][h][j] bf16
  __shared__ float q_lds[G * ND];
  __shared__ float krw_lds[G * NN];
  __shared__ float attn_l[G * ND];
  __shared__ float n1_l[G * ND];
  __shared__ float ff_l[G * 2 * ND];

  const size_t row0 = (size_t)b * NN + i0;
  const size_t kvbase = (size_t)b * NN * ND;

  // ---- prologue staging (coalesced) ----
  q_lds[tid] = Q[row0 * ND + tid];                 // 4 rows x 64
  krw_lds[tid] = kRW[row0 * NN + tid];             // 4 rows x 128
  krw_lds[256 + tid] = kRW[row0 * NN + 256 + tid];

  // B fragments (WeT bf16, L2-hot)
  bf16x8 bfr[2][4];
#pragma unroll
  for (int ks = 0; ks < 2; ++ks)
#pragma unroll
    for (int n0 = 0; n0 < 4; ++n0)
      bfr[ks][n0] = __builtin_bit_cast(
          bf16x8, *(const u16x8*)(&WeT[(n0 * 16 + lrow) * ND + ks * 32 + quad * 8]));

  // K values this lane needs, loaded once (coalesced 4-CL scalar loads),
  // reused for all 4 rows: kreg[mt][n0][reg] = K[j = (w+4mt)*16+quad*4+reg][n0*16+lrow]
  float kreg[2][4][4];
#pragma unroll
  for (int mt = 0; mt < 2; ++mt)
#pragma unroll
    for (int n0 = 0; n0 < 4; ++n0)
#pragma unroll
      for (int reg = 0; reg < 4; ++reg)
        kreg[mt][n0][reg] =
            K[kvbase + (size_t)((w + mt * 4) * 16 + quad * 4 + reg) * ND + n0 * 16 + lrow];

  __syncthreads();

  // ---- phase 1: per row g: coalesced stage -> MFMA -> scores ----
  for (int g = 0; g < G; ++g) {
    const float* ep = e + (row0 + g) * (size_t)(NN * ND);
#pragma unroll
    for (int p = 0; p < 8; ++p) {
      const int idx = p * 1024 + tid * 4;          // 4 KB contiguous per inst
      const float4 v = *(const float4*)(ep + idx);
      const int r = idx >> 6;
      const int c = idx & 63;
      *(ushort4*)(&e_lds[r * 72 + c]) =
          make_ushort4(f2bf(v.x), f2bf(v.y), f2bf(v.z), f2bf(v.w));
    }
    __syncthreads();
#pragma unroll
    for (int mt = 0; mt < 2; ++mt) {
      const int mr = w + mt * 4;
      bf16x8 afr[2];
#pragma unroll
      for (int ks = 0; ks < 2; ++ks)
        afr[ks] = __builtin_bit_cast(
            bf16x8, *(const u16x8*)(&e_lds[(mr * 16 + lrow) * 72 + ks * 32 + quad * 8]));
      f32x4 acc[4];
#pragma unroll
      for (int n0 = 0; n0 < 4; ++n0) acc[n0] = (f32x4){0.f, 0.f, 0.f, 0.f};
#pragma unroll
      for (int ks = 0; ks < 2; ++ks)
#pragma unroll
        for (int n0 = 0; n0 < 4; ++n0)
          acc[n0] =
              __builtin_amdgcn_mfma_f32_16x16x32_bf16(afr[ks], bfr[ks][n0], acc[n0], 0, 0, 0);

      const float4 krw4 = *(const float4*)(&krw_lds[g * NN + mr * 16 + quad * 4]);
      const float* krwp = (const float*)&krw4;
#pragma unroll
      for (int n0 = 0; n0 < 4; ++n0) {
        const float qn = q_lds[g * ND + n0 * 16 + lrow];
        float sv[4];
#pragma unroll
        for (int reg = 0; reg < 4; ++reg) {
          float tv = acc[n0][reg] * qn * kreg[mt][n0][reg];
          tv = DPP_ADD(tv, 0xB1);   // quad_perm xor1
          tv = DPP_ADD(tv, 0x4E);   // quad_perm xor2
          tv = DPP_ADD(tv, 0x141);  // row_half_mirror (completes 8-lane head)
          sv[reg] = __expf(fminf(fmaxf(tv, -5.f), 5.f)) * krwp[reg];
        }
        if ((L & 7) == 0) {
          const int hh = n0 * 2 + ((L >> 3) & 1);
          *(ushort4*)(&S_lds[(g * 8 + hh) * 136 + mr * 16 + quad * 4]) =
              make_ushort4(f2bf(sv[0]), f2bf(sv[1]), f2bf(sv[2]), f2bf(sv[3]));
        }
      }
    }
    __syncthreads();
  }

  // ---- per-wave epilogue for row row0 + w (no cross-wave deps) ----
  const size_t row = row0 + w;
  const int jj = L >> 4;
  const int c4 = L & 15;
  const int hh2 = c4 >> 1;

  // phase 2: attn = (S @ V) / rowsum(S)
  float4 an = make_float4(0.f, 0.f, 0.f, 0.f);
  float den = 0.f;
#pragma unroll 8
  for (int t = 0; t < 32; ++t) {
    const int j = t * 4 + jj;
    const float s = bf2f(S_lds[(w * 8 + hh2) * 136 + j]);
    const float4 v = *(const float4*)(&V[kvbase + (size_t)j * ND + c4 * 4]);
    an.x = fmaf(s, v.x, an.x);
    an.y = fmaf(s, v.y, an.y);
    an.z = fmaf(s, v.z, an.z);
    an.w = fmaf(s, v.w, an.w);
    den += s;
  }
  an = xor_add4(an, 16); an = xor_add4(an, 32);
  den += __shfl_xor(den, 16, 64); den += __shfl_xor(den, 32, 64);
  const float rden = 1.f / fmaxf(den, 1e-6f);
  if (L < 16)
    *(float4*)(&attn_l[w * ND + c4 * 4]) =
        make_float4(an.x * rden, an.y * rden, an.z * rden, an.w * rden);
  __builtin_amdgcn_wave_barrier();

  // phase 3: O-proj + residual + LN1
  float4 o4 = make_float4(0.f, 0.f, 0.f, 0.f);
#pragma unroll 4
  for (int t = 0; t < 16; ++t) {
    const int d = t * 4 + jj;
    const float a = attn_l[w * ND + d];
    const float4 wv = *(const float4*)(&Wo[d * ND + c4 * 4]);
    o4.x = fmaf(a, wv.x, o4.x);
    o4.y = fmaf(a, wv.y, o4.y);
    o4.z = fmaf(a, wv.z, o4.z);
    o4.w = fmaf(a, wv.w, o4.w);
  }
  o4 = xor_add4(o4, 16); o4 = xor_add4(o4, 32);
  const float4 bo4 = *(const float4*)(&bo[c4 * 4]);
  const float4 h4 = *(const float4*)(&h[row * ND + c4 * 4]);
  float4 h1;
  h1.x = h4.x + bo4.x + o4.x;
  h1.y = h4.y + bo4.y + o4.y;
  h1.z = h4.z + bo4.z + o4.z;
  h1.w = h4.w + bo4.w + o4.w;
  const float m1 = wsum64(h1.x + h1.y + h1.z + h1.w) * (1.f / 256.f);
  float4 df;
  df.x = h1.x - m1; df.y = h1.y - m1; df.z = h1.z - m1; df.w = h1.w - m1;
  const float v1 =
      wsum64(df.x * df.x + df.y * df.y + df.z * df.z + df.w * df.w) * (1.f / 256.f);
  const float r1 = rsqrtf(v1 + 1e-5f);
  const float4 g14 = *(const float4*)(&g1[c4 * 4]);
  const float4 be14 = *(const float4*)(&be1[c4 * 4]);
  float4 n14;
  n14.x = df.x * r1 * g14.x + be14.x;
  n14.y = df.y * r1 * g14.y + be14.y;
  n14.z = df.z * r1 * g14.z + be14.z;
  n14.w = df.w * r1 * g14.w + be14.w;
  if (L < 16) *(float4*)(&n1_l[w * ND + c4 * 4]) = n14;
  __builtin_amdgcn_wave_barrier();

  // phase 4: FFN1 + ReLU
  const int dd2 = L >> 5;
  const int c5 = L & 31;
  float4 f4 = make_float4(0.f, 0.f, 0.f, 0.f);
#pragma unroll 8
  for (int t = 0; t < 32; ++t) {
    const int d = t * 2 + dd2;
    const float nv = n1_l[w * ND + d];
    const float4 wv = *(const float4*)(&W1[d * 128 + c5 * 4]);
    f4.x = fmaf(nv, wv.x, f4.x);
    f4.y = fmaf(nv, wv.y, f4.y);
    f4.z = fmaf(nv, wv.z, f4.z);
    f4.w = fmaf(nv, wv.w, f4.w);
  }
  f4 = xor_add4(f4, 32);
  const float4 b14 = *(const float4*)(&b1[c5 * 4]);
  if (L < 32)
    *(float4*)(&ff_l[w * 2 * ND + c5 * 4]) =
        make_float4(fmaxf(f4.x + b14.x, 0.f), fmaxf(f4.y + b14.y, 0.f),
                    fmaxf(f4.z + b14.z, 0.f), fmaxf(f4.w + b14.w, 0.f));
  __builtin_amdgcn_wave_barrier();

  // phase 5: FFN2 + residual + LN2
  float4 q4 = make_float4(0.f, 0.f, 0.f, 0.f);
#pragma unroll 8
  for (int t = 0; t < 32; ++t) {
    const int u = t * 4 + jj;
    const float fv = ff_l[w * 2 * ND + u];
    const float4 wv = *(const float4*)(&W2[u * ND + c4 * 4]);
    q4.x = fmaf(fv, wv.x, q4.x);
    q4.y = fmaf(fv, wv.y, q4.y);
    q4.z = fmaf(fv, wv.z, q4.z);
    q4.w = fmaf(fv, wv.w, q4.w);
  }
  q4 = xor_add4(q4, 16); q4 = xor_add4(q4, 32);
  const float4 b24 = *(const float4*)(&b2[c4 * 4]);
  float4 x4;
  x4.x = n14.x + b24.x + q4.x;
  x4.y = n14.y + b24.y + q4.y;
  x4.z = n14.z + b24.z + q4.z;
  x4.w = n14.w + b24.w + q4.w;
  const float m2 = wsum64(x4.x + x4.y + x4.z + x4.w) * (1.f / 256.f);
  float4 d2;
  d2.x = x4.x - m2; d2.y = x4.y - m2; d2.z = x4.z - m2; d2.w = x4.w - m2;
  const float v2 =
      wsum64(d2.x * d2.x + d2.y * d2.y + d2.z * d2.z + d2.w * d2.w) * (1.f / 256.f);
  const float r2 = rsqrtf(v2 + 1e-5f);
  const float4 g24 = *(const float4*)(&g2[c4 * 4]);
  const float4 be24 = *(const float4*)(&be2[c4 * 4]);
  if (L < 16)
    *(float4*)(&out[row * ND + c4 * 4]) =
        make_float4(d2.x * r2 * g24.x + be24.x, d2.y * r2 * g24.y + be24.y,
                    d2.z * r2 * g24.z + be24.z, d2.w * r2 * g24.w + be24.w);
}

extern "C" void kernel_launch(void* const* d_in, const int* in_sizes, int n_in,
                              void* d_out, int out_size, void* d_ws, size_t ws_size,
                              hipStream_t stream) {
  const float* h   = (const float*)d_in[0];
  const float* e   = (const float*)d_in[2];
  const float* kRW = (const float*)d_in[3];
  const float* Wq  = (const float*)d_in[4];
  const float* Wk  = (const float*)d_in[5];
  const float* We  = (const float*)d_in[6];
  const float* Wv  = (const float*)d_in[7];
  const float* Wo  = (const float*)d_in[8];
  const float* bo  = (const float*)d_in[9];
  const float* g1  = (const float*)d_in[10];
  const float* be1 = (const float*)d_in[11];
  const float* W1  = (const float*)d_in[12];
  const float* b1  = (const float*)d_in[13];
  const float* W2  = (const float*)d_in[14];
  const float* b2  = (const float*)d_in[15];
  const float* g2  = (const float*)d_in[16];
  const float* be2 = (const float*)d_in[17];
  float* out = (float*)d_out;

  float* Q = (float*)d_ws;
  float* K = Q + (size_t)NB * NN * ND;
  float* V = K + (size_t)NB * NN * ND;
  unsigned short* WeT = (unsigned short*)(V + (size_t)NB * NN * ND);

  qkv_kernel<<<NB * NN + 1, 64, 0, stream>>>(h, Wq, Wk, Wv, We, Q, K, V, WeT);
  fused_kernel<<<NB * NN / G, 256, 0, stream>>>(h, e, kRW, Wo, bo, g1, be1,
                                                W1, b1, W2, b2, g2, be2, Q, K, V, WeT, out);
}